// Round 12
// baseline (616.619 us; speedup 1.0000x reference)
//
#include <hip/hip_runtime.h>
#include <stdint.h>

#define NN 50000
#define EE 800000
#define GG 128
#define DF 128
#define DE 256
#define NB 196                       // dst>>8 buckets (256-node ranges)

typedef unsigned short u16;
typedef __bf16 bf16x8 __attribute__((ext_vector_type(8)));
typedef float f32x4 __attribute__((ext_vector_type(4)));
typedef short s16x8 __attribute__((ext_vector_type(8)));

__device__ __forceinline__ float bf2f(u16 u) {
  union { unsigned int i; float f; } x; x.i = ((unsigned int)u) << 16; return x.f;
}
__device__ __forceinline__ u16 f2bf(float f) {
  union { float f; unsigned int i; } x; x.f = f;
  unsigned int i = x.i;
  return (u16)((i + 0x7fffu + ((i >> 16) & 1u)) >> 16);
}

// global -> LDS DMA, 16B/lane; LDS ptr must be WAVE-UNIFORM, HW adds lane*16
__device__ __forceinline__ void async16(const void* g, void* l) {
  __builtin_amdgcn_global_load_lds(
      (const __attribute__((address_space(1))) void*)g,
      (__attribute__((address_space(3))) void*)l,
      16, 0, 0);
}

__device__ __forceinline__ s16x8 vmax8(s16x8 a, s16x8 b) {
  return __builtin_elementwise_max(a, b);   // v_pk_max_i16
}

// ---------------- detect (block 0) + bucket_cnt zero (block 1) ----------------
__global__ void detect_kernel(const u16* __restrict__ xr,
                              const unsigned* __restrict__ ei_words,
                              int* __restrict__ flags, int* __restrict__ bucket_cnt) {
  int tid = threadIdx.x;
  if (blockIdx.x == 1) {
    if (tid < NB) bucket_cnt[tid] = 0;
    return;
  }
  __shared__ int red[2];
  if (tid < 2) red[tid] = 0;
  __syncthreads();
  int found = 0;
  for (int it = 0; it < 32; it++) {
    int i = it * 256 + tid;
    u16 a = xr[2 * i], b = xr[2 * i + 1];
    if (((a >> 7) & 0xFFu) == 0xFFu) found = 1;
    if (((b >> 7) & 0xFFu) == 0xFFu) found = 1;
  }
  if (__ballot(found)) { if ((tid & 63) == 0) atomicOr(&red[0], 1); }
  int nz = 0;
  if (tid < 128) {
    for (int j = 0; j < 4; j++) {
      unsigned w = ei_words[2 * (tid * 4 + j) + 1];
      if (w != 0u) nz = 1;
    }
  }
  if (__ballot(nz)) { if ((tid & 63) == 0) atomicOr(&red[1], 1); }
  __syncthreads();
  if (tid == 0) { flags[0] = red[0]; flags[1] = red[1]; }
}

__device__ __forceinline__ u16 ldw(const void* p, int idx, int f) {
  return f ? f2bf(((const float*)p)[idx]) : ((const u16*)p)[idx];
}

// ---------------- prep: small conversions + x conversion (16B/thread) + edges ----------------
struct ConvSeg { const void* src; u16* dst; int start_blk; int n; };

struct PrepArgs {
  ConvSeg s[12]; int nseg; int conv_blocks;
  const void* x; u16* acat_x; u16* xk;
  const void* ei; const void* batch;
  int* src32; int* dst32; int* batch32; int* bucket_cnt;
};

__global__ void prep_all(PrepArgs A, const int* __restrict__ flags) {
  int f = flags[0];
  int tid = threadIdx.x;
  int b = blockIdx.x;

  if (b < A.conv_blocks) {
    for (int i = 0; i < A.nseg; i++) {
      int nb = (A.s[i].n + 255) >> 8;
      if (b >= A.s[i].start_blk && b < A.s[i].start_blk + nb) {
        int idx = ((b - A.s[i].start_blk) << 8) + tid;
        if (idx < A.s[i].n) A.s[i].dst[idx] = ldw(A.s[i].src, idx, f);
        return;
      }
    }
    return;
  }
  b -= A.conv_blocks;

  if (b < 3125) {                       // x: 8 elems/thread, vectorized
    int i = (b * 256 + tid) * 8;        // NN*DF = 6,400,000 = 3125*256*8 exactly
    int node = i >> 7, d = i & 127;     // d is 8-aligned, stays within row
    union { u16 u[8]; uint4 v; } o, kx;
    if (f) {
      const float4* xp = (const float4*)((const float*)A.x + i);
      float4 a = xp[0], q = xp[1];
      o.u[0] = f2bf(a.x); o.u[1] = f2bf(a.y); o.u[2] = f2bf(a.z); o.u[3] = f2bf(a.w);
      o.u[4] = f2bf(q.x); o.u[5] = f2bf(q.y); o.u[6] = f2bf(q.z); o.u[7] = f2bf(q.w);
    } else {
      o.v = *(const uint4*)((const u16*)A.x + i);
    }
#pragma unroll
    for (int j = 0; j < 8; j++) {
      short s = (short)o.u[j];
      kx.u[j] = (u16)(s ^ ((s >> 15) & 0x7FFF));
    }
    *(uint4*)(A.acat_x + (long)node * 512 + d) = o.v;
    *(uint4*)(A.xk + i) = kx.v;
    return;
  }
  b -= 3125;

  // edges: 391 blocks x 2048 edges, block-local bucket histogram
  __shared__ int h[NB];
  if (tid < NB) h[tid] = 0;
  __syncthreads();
  int i64 = (flags[1] == 0);
  int e0 = b * 2048;
  for (int j = 0; j < 8; j++) {
    int i = e0 + j * 256 + tid;
    if (i < EE) {
      int s, d;
      if (i64) {
        s = (int)((const long long*)A.ei)[i];
        d = (int)((const long long*)A.ei)[EE + i];
      } else {
        s = ((const int*)A.ei)[i];
        d = ((const int*)A.ei)[EE + i];
      }
      s = min(max(s, 0), NN - 1);
      d = min(max(d, 0), NN - 1);
      A.src32[i] = s;
      A.dst32[i] = d;
      atomicAdd(&h[d >> 8], 1);
    }
    if (i < NN) {
      int bv = i64 ? (int)((const long long*)A.batch)[i] : ((const int*)A.batch)[i];
      A.batch32[i] = min(max(bv, 0), GG - 1);
    }
  }
  __syncthreads();
  if (tid < NB) atomicAdd(&A.bucket_cnt[tid], h[tid]);
}

// ---------------- LDS-tiled weight transposes ----------------
struct TransArgs {
  const void* Wl[4]; const void* Wr[4]; const void* Wm[4]; const void* fc1W;
  u16* WcatT[4]; u16* WmT[4]; u16* fc1WT;
};

__global__ __launch_bounds__(256) void transpose_w(TransArgs T, const int* __restrict__ flags) {
  int f = flags[0];
  __shared__ u16 tile[64][65];
  int b = blockIdx.x;
  const void* src; u16* dst; int kt, ntile, Kd; int krow_off = 0;
  if (b < 16) {
    kt = b >> 2; ntile = b & 3; Kd = 256;
    if (kt * 64 < 128) { src = T.Wl[0]; } else { src = T.Wr[0]; krow_off = 128; }
    dst = T.WcatT[0];
  } else if (b < 112) {
    int l = 1 + (b - 16) / 32; int t = (b - 16) % 32;
    kt = t >> 2; ntile = t & 3; Kd = 512;
    if (kt * 64 < 256) { src = T.Wl[l]; } else { src = T.Wr[l]; krow_off = 256; }
    dst = T.WcatT[l];
  } else if (b < 176) {
    int l = (b - 112) / 16; int t = (b - 112) % 16;
    kt = t >> 2; ntile = t & 3; Kd = 256;
    src = T.Wm[l]; dst = T.WmT[l];
  } else {
    int t = b - 176;
    kt = t >> 2; ntile = t & 3; Kd = 1024;
    src = T.fc1W; dst = T.fc1WT;
  }
  int cj = threadIdx.x & 63, rp = threadIdx.x >> 6;
#pragma unroll 4
  for (int p = 0; p < 16; p++) {
    int krow = kt * 64 + p * 4 + rp;
    tile[p * 4 + rp][cj] = ldw(src, (krow - krow_off) * 256 + ntile * 64 + cj, f);
  }
  __syncthreads();
#pragma unroll 4
  for (int p = 0; p < 16; p++) {
    int nrow = ntile * 64 + p * 4 + rp;
    dst[(long)nrow * Kd + kt * 64 + cj] = tile[cj][p * 4 + rp];
  }
}

// ---------------- bucket scan (+ graph starts) ----------------
__global__ void bucket_scan(const int* __restrict__ bucket_cnt, int* __restrict__ bucket_base,
                            int* __restrict__ bucket_cur,
                            const int* __restrict__ batch, int* __restrict__ gs) {
  __shared__ int sh[256];
  int tid = threadIdx.x;
  int x = (tid < NB) ? bucket_cnt[tid] : 0;
  sh[tid] = x;
  __syncthreads();
  for (int off = 1; off < 256; off <<= 1) {
    int v = (tid >= off) ? sh[tid - off] : 0;
    __syncthreads();
    sh[tid] += v;
    __syncthreads();
  }
  if (tid < NB) { bucket_base[tid] = sh[tid] - x; bucket_cur[tid] = sh[tid] - x; }
  if (tid == 0) bucket_base[NB] = EE;
  if (tid <= GG) {
    int g = tid, lo = 0, hi = NN;
    while (lo < hi) { int mid = (lo + hi) >> 1; if (batch[mid] < g) lo = mid + 1; else hi = mid; }
    gs[g] = lo;
  }
}

// ---------------- pass1: scatter edges into bucket-contiguous regions ----------------
__global__ __launch_bounds__(256) void bucket_pass1(
    const int* __restrict__ src32, const int* __restrict__ dst32,
    int* __restrict__ bucket_cur, unsigned* __restrict__ bucket_buf) {
  __shared__ int lcnt[NB];
  __shared__ int lbase[NB];
  int tid = threadIdx.x, b = blockIdx.x;
  if (tid < NB) lcnt[tid] = 0;
  __syncthreads();
  int e0 = b * 2048;
  int lofs[8]; unsigned pk[8]; int bk[8];
#pragma unroll
  for (int j = 0; j < 8; j++) {
    int i = e0 + j * 256 + tid;
    if (i < EE) {
      int s = src32[i], d = dst32[i];
      bk[j] = d >> 8;
      pk[j] = ((unsigned)s << 8) | (unsigned)(d & 255);
      lofs[j] = atomicAdd(&lcnt[bk[j]], 1);
    } else bk[j] = -1;
  }
  __syncthreads();
  if (tid < NB) lbase[tid] = atomicAdd(&bucket_cur[tid], lcnt[tid]);
  __syncthreads();
#pragma unroll
  for (int j = 0; j < 8; j++)
    if (bk[j] >= 0)
      bucket_buf[lbase[bk[j]] + lofs[j]] = pk[j];
}

// ---------------- pass2: per-bucket local CSR -> row_ptr + col_src ----------------
__global__ __launch_bounds__(256) void bucket_pass2(
    const unsigned* __restrict__ bucket_buf, const int* __restrict__ bucket_base,
    int* __restrict__ col_src, int* __restrict__ row_ptr) {
  __shared__ int cnt[256];
  __shared__ int sh[256];
  __shared__ int cur[256];
  int tid = threadIdx.x, b = blockIdx.x;
  int ebase = bucket_base[b], eend = bucket_base[b + 1];
  cnt[tid] = 0;
  __syncthreads();
  for (int e = ebase + tid; e < eend; e += 256)
    atomicAdd(&cnt[bucket_buf[e] & 255u], 1);
  __syncthreads();
  int x = cnt[tid];
  sh[tid] = x;
  __syncthreads();
  for (int off = 1; off < 256; off <<= 1) {
    int v = (tid >= off) ? sh[tid - off] : 0;
    __syncthreads();
    sh[tid] += v;
    __syncthreads();
  }
  int node = b * 256 + tid;
  if (node < NN) row_ptr[node + 1] = ebase + sh[tid];
  cur[tid] = ebase + sh[tid] - x;
  __syncthreads();
  for (int e = ebase + tid; e < eend; e += 256) {
    unsigned p = bucket_buf[e];
    int slot = atomicAdd(&cur[p & 255u], 1);
    col_src[slot] = (int)(p >> 8);
  }
  if (b == 0 && tid == 0) row_ptr[0] = 0;
}

// ---------------- per-node max aggregation (packed i16, 4-deep ILP) ----------------
template <int LPR, bool KEYED>
__global__ __launch_bounds__(256) void segmax_kernel(
    const u16* __restrict__ feat, int fstride,
    const int* __restrict__ row_ptr, const int* __restrict__ col_src,
    u16* __restrict__ agg_out, int ostride, int n) {
  constexpr int R = 64 / LPR;
  int node = blockIdx.x * 4 + (threadIdx.x >> 6);
  if (node >= n) return;
  int lane = threadIdx.x & 63;
  int sub = lane / LPR;
  int cp = lane % LPR;
  int beg = row_ptr[node], end = row_ptr[node + 1];
  s16x8 m = (s16x8)(short)(KEYED ? (short)0x807F : (short)0);
  const u16* fb = feat + cp * 8;

  int e = beg + sub;
  for (; e + 3 * R < end; e += 4 * R) {
    int s0 = col_src[e];
    int s1 = col_src[e + R];
    int s2 = col_src[e + 2 * R];
    int s3 = col_src[e + 3 * R];
    s16x8 v0 = *(const s16x8*)(fb + (long)s0 * fstride);
    s16x8 v1 = *(const s16x8*)(fb + (long)s1 * fstride);
    s16x8 v2 = *(const s16x8*)(fb + (long)s2 * fstride);
    s16x8 v3 = *(const s16x8*)(fb + (long)s3 * fstride);
    m = vmax8(m, vmax8(vmax8(v0, v1), vmax8(v2, v3)));
  }
  for (; e < end; e += R)
    m = vmax8(m, *(const s16x8*)(fb + (long)col_src[e] * fstride));

#pragma unroll
  for (int d = LPR; d < 64; d <<= 1) {
    union { s16x8 s; int i[4]; } t;
    t.s = m;
#pragma unroll
    for (int j = 0; j < 4; j++) t.i[j] = __shfl_xor(t.i[j], d);
    m = vmax8(m, t.s);
  }

  if (sub == 0) {
    if (KEYED) {
      if (beg == end) {
        m = (s16x8)(short)0;
      } else {
        s16x8 sp = (m >> 15) & (short)0x7FFF;
        m = m ^ sp;
      }
    }
    *(s16x8*)(agg_out + (long)node * ostride + cp * 8) = m;
  }
}

// ---------------- MFMA GEMM: 64x256 tile, 256 threads (4 waves), XOR-swizzled LDS ----------
// 20KB LDS + 4 waves -> up to 8 blocks/CU; grid 782 ~ 3 co-resident blocks/CU for overlap.
__global__ __launch_bounds__(256) void gemm64(
    const u16* __restrict__ A, int lda, int K,
    const u16* __restrict__ BT,          // [256][K]
    const u16* __restrict__ bias,
    u16* __restrict__ C, int ldc, int M, int relu_flag) {
  __shared__ u16 lsA[64 * 32];    // 4 KB
  __shared__ u16 lsB[256 * 32];   // 16 KB
  int tid = threadIdx.x;
  int lane = tid & 63, w = tid >> 6;
  int bm = blockIdx.x;
  int wn = w << 6;
  int ln15 = lane & 15, quad = lane >> 4;

  f32x4 acc[4][4] = {};

  int r = tid >> 2;                    // 0..63
  int c = (tid & 3) ^ (r & 3);         // XOR chunk swizzle ((r+64k)&3 == r&3)
  const u16* gA = A + (long)min(bm * 64 + r, M - 1) * lda + c * 8;
  const u16* g0 = BT + (long)r * K + c * 8;
  const u16* g1 = BT + (long)(r + 64) * K + c * 8;
  const u16* g2 = BT + (long)(r + 128) * K + c * 8;
  const u16* g3 = BT + (long)(r + 192) * K + c * 8;
  u16* lA  = lsA + w * 512;            // wave-uniform bases (HW adds lane*16B)
  u16* lB0 = lsB + w * 512;
  u16* lB1 = lB0 + 2048;
  u16* lB2 = lB0 + 4096;
  u16* lB3 = lB0 + 6144;
  int swz = (quad ^ (ln15 & 3)) << 3;

  for (int k0 = 0; k0 < K; k0 += 32) {
    async16(gA + k0, lA);
    async16(g0 + k0, lB0);
    async16(g1 + k0, lB1);
    async16(g2 + k0, lB2);
    async16(g3 + k0, lB3);
    __syncthreads();
    bf16x8 af[4], bfr[4];
#pragma unroll
    for (int t = 0; t < 4; t++) {
      af[t]  = *(const bf16x8*)(lsA + (t * 16 + ln15) * 32 + swz);
      bfr[t] = *(const bf16x8*)(lsB + (wn + t * 16 + ln15) * 32 + swz);
    }
#pragma unroll
    for (int mt = 0; mt < 4; mt++)
#pragma unroll
      for (int nt = 0; nt < 4; nt++)
        acc[mt][nt] = __builtin_amdgcn_mfma_f32_16x16x32_bf16(af[mt], bfr[nt], acc[mt][nt], 0, 0, 0);
    __syncthreads();
  }

  float bv[4];
#pragma unroll
  for (int nt = 0; nt < 4; nt++)
    bv[nt] = bf2f(bias[wn + nt * 16 + ln15]);

#pragma unroll
  for (int mt = 0; mt < 4; mt++) {
    int row0 = bm * 64 + mt * 16 + quad * 4;
#pragma unroll
    for (int rr = 0; rr < 4; rr++) {
      int row = row0 + rr;
      if (row < M) {
#pragma unroll
        for (int nt = 0; nt < 4; nt++) {
          float v = acc[mt][nt][rr] + bv[nt];
          if (relu_flag) v = fmaxf(v, 0.f);
          C[(long)row * ldc + wn + nt * 16 + ln15] = f2bf(v);
        }
      }
    }
  }
}

// ---------------- per-layer global max pool ----------------
__global__ void pool_kernel(const u16* __restrict__ h, const int* __restrict__ gs,
                            u16* __restrict__ g_pool, int l) {
  int g = blockIdx.x;
  int chunk = threadIdx.x & 31;
  int rg = threadIdx.x >> 5;
  int beg = gs[g], end = gs[g + 1];
  s16x8 m = (s16x8)(short)0;
  const u16* hp = h + chunk * 8;
  for (int n = beg + rg; n < end; n += 32)
    m = vmax8(m, *(const s16x8*)(hp + (long)n * 512));
  __shared__ s16x8 red[32][32];
  red[rg][chunk] = m;
  __syncthreads();
  for (int s = 16; s >= 1; s >>= 1) {
    if (rg < s) red[rg][chunk] = vmax8(red[rg][chunk], red[rg + s][chunk]);
    __syncthreads();
  }
  if (rg == 0)
    *(s16x8*)(g_pool + g * 1024 + l * 256 + chunk * 8) = red[0][chunk];
}

// ---------------- fc1 split-K GEMM: 8 blocks, f32 partials ----------------
__global__ __launch_bounds__(256) void fc1_gemm(
    const u16* __restrict__ A,      // gpool [128][1024] bf16
    const u16* __restrict__ BT,     // fc1WT [256][1024]
    float* __restrict__ Cpart) {    // [4][128][256]
  __shared__ u16 lsA[128 * 32];
  __shared__ u16 lsB[128 * 32];
  int tid = threadIdx.x;
  int lane = tid & 63, w = tid >> 6;
  int slice = blockIdx.x >> 1, bn = blockIdx.x & 1;
  int wm = (w & 1) << 6, wn = (w >> 1) << 6;
  int ln15 = lane & 15, quad = lane >> 4;

  f32x4 acc[4][4] = {};

  int cm = lane >> 2;
  int ck = (lane & 3) << 3;
  int kb = slice * 256;

  const u16* gA0 = A + (long)(w * 16 + cm) * 1024 + kb + ck;
  const u16* gA1 = A + (long)((w + 4) * 16 + cm) * 1024 + kb + ck;
  const u16* gB0 = BT + (long)(bn * 128 + w * 16 + cm) * 1024 + kb + ck;
  const u16* gB1 = BT + (long)(bn * 128 + (w + 4) * 16 + cm) * 1024 + kb + ck;
  u16* lA0 = lsA + w * 512;
  u16* lA1 = lsA + (w + 4) * 512;
  u16* lB0 = lsB + w * 512;
  u16* lB1 = lsB + (w + 4) * 512;

  for (int k0 = 0; k0 < 256; k0 += 32) {
    async16(gA0 + k0, lA0);
    async16(gA1 + k0, lA1);
    async16(gB0 + k0, lB0);
    async16(gB1 + k0, lB1);
    __syncthreads();
    bf16x8 af[4], bfr[4];
#pragma unroll
    for (int t = 0; t < 4; t++) {
      af[t]  = *(const bf16x8*)(lsA + (wm + t * 16 + ln15) * 32 + quad * 8);
      bfr[t] = *(const bf16x8*)(lsB + (wn + t * 16 + ln15) * 32 + quad * 8);
    }
#pragma unroll
    for (int mt = 0; mt < 4; mt++)
#pragma unroll
      for (int nt = 0; nt < 4; nt++)
        acc[mt][nt] = __builtin_amdgcn_mfma_f32_16x16x32_bf16(af[mt], bfr[nt], acc[mt][nt], 0, 0, 0);
    __syncthreads();
  }

  float* Cb = Cpart + slice * (GG * 256);
#pragma unroll
  for (int mt = 0; mt < 4; mt++) {
    int row0 = wm + mt * 16 + quad * 4;
#pragma unroll
    for (int r = 0; r < 4; r++)
#pragma unroll
      for (int nt = 0; nt < 4; nt++)
        Cb[(row0 + r) * 256 + bn * 128 + wn + nt * 16 + ln15] = acc[mt][nt][r];
  }
}

// ---------------- fc2 + head ----------------
__global__ void fc2_head(const float* __restrict__ fc1part,
                         const u16* __restrict__ fc1b,
                         const u16* __restrict__ W,
                         const u16* __restrict__ b,
                         void* __restrict__ outbuf, const int* __restrict__ flags) {
  int g = blockIdx.x, t = threadIdx.x;
  __shared__ float lr[256];
  __shared__ float ps[144];
  __shared__ float sv[18];
  __shared__ float sred[2];
  float v = bf2f(fc1b[t]);
#pragma unroll
  for (int s = 0; s < 4; s++) v += fc1part[s * (GG * 256) + g * 256 + t];
  v = fmaxf(v, 0.f);
  lr[t] = v;
  if (flags[0]) ((float*)outbuf)[4608 + g * 256 + t] = v;
  else          ((u16*)outbuf)[4608 + g * 256 + t] = f2bf(v);
  __syncthreads();
  if (t < 144) {
    int o = t % 18, s = t / 18;
    float acc = 0.f;
    int k0 = s * 32;
#pragma unroll 8
    for (int k = k0; k < k0 + 32; k++)
      acc += lr[k] * bf2f(W[k * 18 + o]);
    ps[t] = acc;
  }
  __syncthreads();
  if (t < 18) {
    float acc = bf2f(b[t]);
#pragma unroll
    for (int s = 0; s < 8; s++) acc += ps[s * 18 + t];
    sv[t] = acc;
  }
  __syncthreads();
  if (t == 0) {
    float mx = sv[0];
    for (int i = 1; i < 18; i++) mx = fmaxf(mx, sv[i]);
    float s = 0.f;
    for (int i = 0; i < 18; i++) s += expf(sv[i] - mx);
    sred[0] = mx; sred[1] = logf(s);
  }
  __syncthreads();
  if (t < 18) {
    float raw = sv[t];
    float lsm = raw - sred[0] - sred[1];
    if (flags[0]) {
      ((float*)outbuf)[g * 18 + t] = lsm;
      ((float*)outbuf)[2304 + g * 18 + t] = raw;
    } else {
      ((u16*)outbuf)[g * 18 + t] = f2bf(lsm);
      ((u16*)outbuf)[2304 + g * 18 + t] = f2bf(raw);
    }
  }
}

extern "C" void kernel_launch(void* const* d_in, const int* in_sizes, int n_in,
                              void* d_out, int out_size, void* d_ws, size_t ws_size,
                              hipStream_t stream) {
  (void)in_sizes; (void)n_in; (void)out_size; (void)ws_size;
  const void* x = d_in[0];
  const void* ei = d_in[1];
  const void* batch = d_in[2];
  const void *Wl[4], *bl[4], *Wr[4], *Wm[4], *bm[4];
  for (int l = 0; l < 4; l++) {
    Wl[l] = d_in[3 + l * 5 + 0];
    bl[l] = d_in[3 + l * 5 + 1];
    Wr[l] = d_in[3 + l * 5 + 2];
    Wm[l] = d_in[3 + l * 5 + 3];
    bm[l] = d_in[3 + l * 5 + 4];
  }
  const void* fc1W = d_in[23];
  const void* fc1b = d_in[24];
  const void* fc2W = d_in[25];
  const void* fc2b = d_in[26];

  char* ws = (char*)d_ws;
  size_t off = 0;
  auto alloc = [&](size_t bytes) -> void* {
    void* p = ws + off;
    off = (off + bytes + 255) & ~(size_t)255;
    return p;
  };
  int* flags       = (int*)alloc(16);
  int* row_ptr     = (int*)alloc((NN + 1) * sizeof(int));
  int* bucket_cnt  = (int*)alloc(NB * sizeof(int));
  int* bucket_base = (int*)alloc((NB + 1) * sizeof(int));
  int* bucket_cur  = (int*)alloc(NB * sizeof(int));
  unsigned* bucket_buf = (unsigned*)alloc((size_t)EE * sizeof(unsigned));
  int* col_src = (int*)alloc((size_t)EE * sizeof(int));
  int* src32   = (int*)alloc((size_t)EE * sizeof(int));
  int* dst32   = (int*)alloc((size_t)EE * sizeof(int));
  int* batch32 = (int*)alloc(NN * sizeof(int));
  int* gs      = (int*)alloc((GG + 1) * sizeof(int));
  u16* WcatT[4]; for (int l = 0; l < 4; l++) WcatT[l] = (u16*)alloc(256 * 512 * 2);
  u16* WmT[4];   for (int l = 0; l < 4; l++) WmT[l]   = (u16*)alloc(256 * 256 * 2);
  u16* bl_bf[4]; for (int l = 0; l < 4; l++) bl_bf[l] = (u16*)alloc(256 * 2);
  u16* bm_bf[4]; for (int l = 0; l < 4; l++) bm_bf[l] = (u16*)alloc(256 * 2);
  u16* fc1WT   = (u16*)alloc(256 * 1024 * 2);
  u16* fc1b_bf = (u16*)alloc(256 * 2);
  u16* fc2W_bf = (u16*)alloc(256 * 18 * 2);
  u16* fc2b_bf = (u16*)alloc(18 * 2);
  u16* xk      = (u16*)alloc((size_t)NN * DF * 2);
  u16* Acat    = (u16*)alloc((size_t)NN * 512 * 2);
  u16* tmp     = (u16*)alloc((size_t)NN * 256 * 2);
  u16* gpool   = (u16*)alloc(GG * 1024 * 2);
  float* fc1part = (float*)alloc(4 * GG * 256 * sizeof(float));

  detect_kernel<<<2, 256, 0, stream>>>((const u16*)x, (const unsigned*)ei, flags, bucket_cnt);

  TransArgs TA;
  for (int l = 0; l < 4; l++) {
    TA.Wl[l] = Wl[l]; TA.Wr[l] = Wr[l]; TA.Wm[l] = Wm[l];
    TA.WcatT[l] = WcatT[l]; TA.WmT[l] = WmT[l];
  }
  TA.fc1W = fc1W; TA.fc1WT = fc1WT;
  transpose_w<<<240, 256, 0, stream>>>(TA, flags);

  PrepArgs PA;
  int blk = 0, si = 0;
  auto addseg = [&](const void* s, u16* d, int n) {
    PA.s[si].src = s; PA.s[si].dst = d; PA.s[si].start_blk = blk; PA.s[si].n = n;
    blk += (n + 255) / 256; si++;
  };
  addseg(fc2W, fc2W_bf, 256 * 18);
  for (int l = 0; l < 4; l++) addseg(bl[l], bl_bf[l], 256);
  for (int l = 0; l < 4; l++) addseg(bm[l], bm_bf[l], 256);
  addseg(fc1b, fc1b_bf, 256);
  addseg(fc2b, fc2b_bf, 18);
  PA.nseg = si; PA.conv_blocks = blk;
  PA.x = x; PA.acat_x = Acat + DF; PA.xk = xk;
  PA.ei = ei; PA.batch = batch;
  PA.src32 = src32; PA.dst32 = dst32; PA.batch32 = batch32; PA.bucket_cnt = bucket_cnt;
  prep_all<<<PA.conv_blocks + 3125 + 391, 256, 0, stream>>>(PA, flags);

  bucket_scan<<<1, 256, 0, stream>>>(bucket_cnt, bucket_base, bucket_cur, batch32, gs);
  bucket_pass1<<<391, 256, 0, stream>>>(src32, dst32, bucket_cur, bucket_buf);
  bucket_pass2<<<NB, 256, 0, stream>>>(bucket_buf, bucket_base, col_src, row_ptr);

  int segblocks = (NN + 3) / 4;
  int gemmgrid = (NN + 63) / 64;    // 782

  for (int l = 0; l < 4; l++) {
    if (l == 0) {
      segmax_kernel<16, true><<<segblocks, 256, 0, stream>>>(xk, DF, row_ptr, col_src,
                                                             Acat, 512, NN);
    } else {
      segmax_kernel<32, false><<<segblocks, 256, 0, stream>>>(Acat + 256, 512, row_ptr, col_src,
                                                              Acat, 512, NN);
    }
    int K = (l == 0) ? 256 : 512;
    gemm64<<<gemmgrid, 256, 0, stream>>>(Acat, 512, K, WcatT[l], bl_bf[l], tmp, 256, NN, 0);
    gemm64<<<gemmgrid, 256, 0, stream>>>(tmp, 256, 256, WmT[l], bm_bf[l], Acat + 256, 512, NN, 1);
    pool_kernel<<<GG, 1024, 0, stream>>>(Acat + 256, gs, gpool, l);
  }

  fc1_gemm<<<8, 256, 0, stream>>>(gpool, fc1WT, fc1part);
  fc2_head<<<GG, 256, 0, stream>>>(fc1part, fc1b_bf, fc2W_bf, fc2b_bf, d_out, flags);
}

// Round 13
// 552.535 us; speedup vs baseline: 1.1160x; 1.1160x over previous
//
#include <hip/hip_runtime.h>
#include <stdint.h>

#define NN 50000
#define EE 800000
#define GG 128
#define DF 128
#define DE 256
#define NB 196                       // dst>>8 buckets (256-node ranges)

typedef unsigned short u16;
typedef __bf16 bf16x8 __attribute__((ext_vector_type(8)));
typedef float f32x4 __attribute__((ext_vector_type(4)));
typedef short s16x8 __attribute__((ext_vector_type(8)));

__device__ __forceinline__ float bf2f(u16 u) {
  union { unsigned int i; float f; } x; x.i = ((unsigned int)u) << 16; return x.f;
}
__device__ __forceinline__ u16 f2bf(float f) {
  union { float f; unsigned int i; } x; x.f = f;
  unsigned int i = x.i;
  return (u16)((i + 0x7fffu + ((i >> 16) & 1u)) >> 16);
}

// global -> LDS DMA, 16B/lane; LDS ptr must be WAVE-UNIFORM, HW adds lane*16
__device__ __forceinline__ void async16(const void* g, void* l) {
  __builtin_amdgcn_global_load_lds(
      (const __attribute__((address_space(1))) void*)g,
      (__attribute__((address_space(3))) void*)l,
      16, 0, 0);
}

__device__ __forceinline__ s16x8 vmax8(s16x8 a, s16x8 b) {
  return __builtin_elementwise_max(a, b);   // v_pk_max_i16
}

// ---------------- detect (block 0) + bucket_cnt zero (block 1) ----------------
__global__ void detect_kernel(const u16* __restrict__ xr,
                              const unsigned* __restrict__ ei_words,
                              int* __restrict__ flags, int* __restrict__ bucket_cnt) {
  int tid = threadIdx.x;
  if (blockIdx.x == 1) {
    if (tid < NB) bucket_cnt[tid] = 0;
    return;
  }
  __shared__ int red[2];
  if (tid < 2) red[tid] = 0;
  __syncthreads();
  int found = 0;
  for (int it = 0; it < 32; it++) {
    int i = it * 256 + tid;
    u16 a = xr[2 * i], b = xr[2 * i + 1];
    if (((a >> 7) & 0xFFu) == 0xFFu) found = 1;
    if (((b >> 7) & 0xFFu) == 0xFFu) found = 1;
  }
  if (__ballot(found)) { if ((tid & 63) == 0) atomicOr(&red[0], 1); }
  int nz = 0;
  if (tid < 128) {
    for (int j = 0; j < 4; j++) {
      unsigned w = ei_words[2 * (tid * 4 + j) + 1];
      if (w != 0u) nz = 1;
    }
  }
  if (__ballot(nz)) { if ((tid & 63) == 0) atomicOr(&red[1], 1); }
  __syncthreads();
  if (tid == 0) { flags[0] = red[0]; flags[1] = red[1]; }
}

__device__ __forceinline__ u16 ldw(const void* p, int idx, int f) {
  return f ? f2bf(((const float*)p)[idx]) : ((const u16*)p)[idx];
}

// ---------------- prep: small conversions + x conversion (16B/thread) + edges ----------------
struct ConvSeg { const void* src; u16* dst; int start_blk; int n; };

struct PrepArgs {
  ConvSeg s[12]; int nseg; int conv_blocks;
  const void* x; u16* acat_x; u16* xk;
  const void* ei; const void* batch;
  int* src32; int* dst32; int* batch32; int* bucket_cnt;
};

__global__ void prep_all(PrepArgs A, const int* __restrict__ flags) {
  int f = flags[0];
  int tid = threadIdx.x;
  int b = blockIdx.x;

  if (b < A.conv_blocks) {
    for (int i = 0; i < A.nseg; i++) {
      int nb = (A.s[i].n + 255) >> 8;
      if (b >= A.s[i].start_blk && b < A.s[i].start_blk + nb) {
        int idx = ((b - A.s[i].start_blk) << 8) + tid;
        if (idx < A.s[i].n) A.s[i].dst[idx] = ldw(A.s[i].src, idx, f);
        return;
      }
    }
    return;
  }
  b -= A.conv_blocks;

  if (b < 3125) {                       // x: 8 elems/thread, vectorized
    int i = (b * 256 + tid) * 8;        // NN*DF = 6,400,000 = 3125*256*8 exactly
    int node = i >> 7, d = i & 127;     // d is 8-aligned, stays within row
    union { u16 u[8]; uint4 v; } o, kx;
    if (f) {
      const float4* xp = (const float4*)((const float*)A.x + i);
      float4 a = xp[0], q = xp[1];
      o.u[0] = f2bf(a.x); o.u[1] = f2bf(a.y); o.u[2] = f2bf(a.z); o.u[3] = f2bf(a.w);
      o.u[4] = f2bf(q.x); o.u[5] = f2bf(q.y); o.u[6] = f2bf(q.z); o.u[7] = f2bf(q.w);
    } else {
      o.v = *(const uint4*)((const u16*)A.x + i);
    }
#pragma unroll
    for (int j = 0; j < 8; j++) {
      short s = (short)o.u[j];
      kx.u[j] = (u16)(s ^ ((s >> 15) & 0x7FFF));
    }
    *(uint4*)(A.acat_x + (long)node * 512 + d) = o.v;
    *(uint4*)(A.xk + i) = kx.v;
    return;
  }
  b -= 3125;

  // edges: 391 blocks x 2048 edges, block-local bucket histogram
  __shared__ int h[NB];
  if (tid < NB) h[tid] = 0;
  __syncthreads();
  int i64 = (flags[1] == 0);
  int e0 = b * 2048;
  for (int j = 0; j < 8; j++) {
    int i = e0 + j * 256 + tid;
    if (i < EE) {
      int s, d;
      if (i64) {
        s = (int)((const long long*)A.ei)[i];
        d = (int)((const long long*)A.ei)[EE + i];
      } else {
        s = ((const int*)A.ei)[i];
        d = ((const int*)A.ei)[EE + i];
      }
      s = min(max(s, 0), NN - 1);
      d = min(max(d, 0), NN - 1);
      A.src32[i] = s;
      A.dst32[i] = d;
      atomicAdd(&h[d >> 8], 1);
    }
    if (i < NN) {
      int bv = i64 ? (int)((const long long*)A.batch)[i] : ((const int*)A.batch)[i];
      A.batch32[i] = min(max(bv, 0), GG - 1);
    }
  }
  __syncthreads();
  if (tid < NB) atomicAdd(&A.bucket_cnt[tid], h[tid]);
}

// ---------------- LDS-tiled weight transposes ----------------
struct TransArgs {
  const void* Wl[4]; const void* Wr[4]; const void* Wm[4]; const void* fc1W;
  u16* WcatT[4]; u16* WmT[4]; u16* fc1WT;
};

__global__ __launch_bounds__(256) void transpose_w(TransArgs T, const int* __restrict__ flags) {
  int f = flags[0];
  __shared__ u16 tile[64][65];
  int b = blockIdx.x;
  const void* src; u16* dst; int kt, ntile, Kd; int krow_off = 0;
  if (b < 16) {
    kt = b >> 2; ntile = b & 3; Kd = 256;
    if (kt * 64 < 128) { src = T.Wl[0]; } else { src = T.Wr[0]; krow_off = 128; }
    dst = T.WcatT[0];
  } else if (b < 112) {
    int l = 1 + (b - 16) / 32; int t = (b - 16) % 32;
    kt = t >> 2; ntile = t & 3; Kd = 512;
    if (kt * 64 < 256) { src = T.Wl[l]; } else { src = T.Wr[l]; krow_off = 256; }
    dst = T.WcatT[l];
  } else if (b < 176) {
    int l = (b - 112) / 16; int t = (b - 112) % 16;
    kt = t >> 2; ntile = t & 3; Kd = 256;
    src = T.Wm[l]; dst = T.WmT[l];
  } else {
    int t = b - 176;
    kt = t >> 2; ntile = t & 3; Kd = 1024;
    src = T.fc1W; dst = T.fc1WT;
  }
  int cj = threadIdx.x & 63, rp = threadIdx.x >> 6;
#pragma unroll 4
  for (int p = 0; p < 16; p++) {
    int krow = kt * 64 + p * 4 + rp;
    tile[p * 4 + rp][cj] = ldw(src, (krow - krow_off) * 256 + ntile * 64 + cj, f);
  }
  __syncthreads();
#pragma unroll 4
  for (int p = 0; p < 16; p++) {
    int nrow = ntile * 64 + p * 4 + rp;
    dst[(long)nrow * Kd + kt * 64 + cj] = tile[cj][p * 4 + rp];
  }
}

// ---------------- bucket scan (+ graph starts) ----------------
__global__ void bucket_scan(const int* __restrict__ bucket_cnt, int* __restrict__ bucket_base,
                            int* __restrict__ bucket_cur,
                            const int* __restrict__ batch, int* __restrict__ gs) {
  __shared__ int sh[256];
  int tid = threadIdx.x;
  int x = (tid < NB) ? bucket_cnt[tid] : 0;
  sh[tid] = x;
  __syncthreads();
  for (int off = 1; off < 256; off <<= 1) {
    int v = (tid >= off) ? sh[tid - off] : 0;
    __syncthreads();
    sh[tid] += v;
    __syncthreads();
  }
  if (tid < NB) { bucket_base[tid] = sh[tid] - x; bucket_cur[tid] = sh[tid] - x; }
  if (tid == 0) bucket_base[NB] = EE;
  if (tid <= GG) {
    int g = tid, lo = 0, hi = NN;
    while (lo < hi) { int mid = (lo + hi) >> 1; if (batch[mid] < g) lo = mid + 1; else hi = mid; }
    gs[g] = lo;
  }
}

// ---------------- pass1: scatter edges into bucket-contiguous regions ----------------
__global__ __launch_bounds__(256) void bucket_pass1(
    const int* __restrict__ src32, const int* __restrict__ dst32,
    int* __restrict__ bucket_cur, unsigned* __restrict__ bucket_buf) {
  __shared__ int lcnt[NB];
  __shared__ int lbase[NB];
  int tid = threadIdx.x, b = blockIdx.x;
  if (tid < NB) lcnt[tid] = 0;
  __syncthreads();
  int e0 = b * 2048;
  int lofs[8]; unsigned pk[8]; int bk[8];
#pragma unroll
  for (int j = 0; j < 8; j++) {
    int i = e0 + j * 256 + tid;
    if (i < EE) {
      int s = src32[i], d = dst32[i];
      bk[j] = d >> 8;
      pk[j] = ((unsigned)s << 8) | (unsigned)(d & 255);
      lofs[j] = atomicAdd(&lcnt[bk[j]], 1);
    } else bk[j] = -1;
  }
  __syncthreads();
  if (tid < NB) lbase[tid] = atomicAdd(&bucket_cur[tid], lcnt[tid]);
  __syncthreads();
#pragma unroll
  for (int j = 0; j < 8; j++)
    if (bk[j] >= 0)
      bucket_buf[lbase[bk[j]] + lofs[j]] = pk[j];
}

// ---------------- pass2: per-bucket local CSR -> row_ptr + col_src ----------------
__global__ __launch_bounds__(256) void bucket_pass2(
    const unsigned* __restrict__ bucket_buf, const int* __restrict__ bucket_base,
    int* __restrict__ col_src, int* __restrict__ row_ptr) {
  __shared__ int cnt[256];
  __shared__ int sh[256];
  __shared__ int cur[256];
  int tid = threadIdx.x, b = blockIdx.x;
  int ebase = bucket_base[b], eend = bucket_base[b + 1];
  cnt[tid] = 0;
  __syncthreads();
  for (int e = ebase + tid; e < eend; e += 256)
    atomicAdd(&cnt[bucket_buf[e] & 255u], 1);
  __syncthreads();
  int x = cnt[tid];
  sh[tid] = x;
  __syncthreads();
  for (int off = 1; off < 256; off <<= 1) {
    int v = (tid >= off) ? sh[tid - off] : 0;
    __syncthreads();
    sh[tid] += v;
    __syncthreads();
  }
  int node = b * 256 + tid;
  if (node < NN) row_ptr[node + 1] = ebase + sh[tid];
  cur[tid] = ebase + sh[tid] - x;
  __syncthreads();
  for (int e = ebase + tid; e < eend; e += 256) {
    unsigned p = bucket_buf[e];
    int slot = atomicAdd(&cur[p & 255u], 1);
    col_src[slot] = (int)(p >> 8);
  }
  if (b == 0 && tid == 0) row_ptr[0] = 0;
}

// ---------------- per-node max aggregation (packed i16, 4-deep ILP) ----------------
template <int LPR, bool KEYED>
__global__ __launch_bounds__(256) void segmax_kernel(
    const u16* __restrict__ feat, int fstride,
    const int* __restrict__ row_ptr, const int* __restrict__ col_src,
    u16* __restrict__ agg_out, int ostride, int n) {
  constexpr int R = 64 / LPR;
  int node = blockIdx.x * 4 + (threadIdx.x >> 6);
  if (node >= n) return;
  int lane = threadIdx.x & 63;
  int sub = lane / LPR;
  int cp = lane % LPR;
  int beg = row_ptr[node], end = row_ptr[node + 1];
  s16x8 m = (s16x8)(short)(KEYED ? (short)0x807F : (short)0);
  const u16* fb = feat + cp * 8;

  int e = beg + sub;
  for (; e + 3 * R < end; e += 4 * R) {
    int s0 = col_src[e];
    int s1 = col_src[e + R];
    int s2 = col_src[e + 2 * R];
    int s3 = col_src[e + 3 * R];
    s16x8 v0 = *(const s16x8*)(fb + (long)s0 * fstride);
    s16x8 v1 = *(const s16x8*)(fb + (long)s1 * fstride);
    s16x8 v2 = *(const s16x8*)(fb + (long)s2 * fstride);
    s16x8 v3 = *(const s16x8*)(fb + (long)s3 * fstride);
    m = vmax8(m, vmax8(vmax8(v0, v1), vmax8(v2, v3)));
  }
  for (; e < end; e += R)
    m = vmax8(m, *(const s16x8*)(fb + (long)col_src[e] * fstride));

#pragma unroll
  for (int d = LPR; d < 64; d <<= 1) {
    union { s16x8 s; int i[4]; } t;
    t.s = m;
#pragma unroll
    for (int j = 0; j < 4; j++) t.i[j] = __shfl_xor(t.i[j], d);
    m = vmax8(m, t.s);
  }

  if (sub == 0) {
    if (KEYED) {
      if (beg == end) {
        m = (s16x8)(short)0;
      } else {
        s16x8 sp = (m >> 15) & (short)0x7FFF;
        m = m ^ sp;
      }
    }
    *(s16x8*)(agg_out + (long)node * ostride + cp * 8) = m;
  }
}

// ---------------- MFMA GEMM (r10 best-measured): 128x256 tile, 512 threads, XOR swizzle ----
__global__ __launch_bounds__(512) void gemm256w(
    const u16* __restrict__ A, int lda, int K,
    const u16* __restrict__ BT,          // [256][K]
    const u16* __restrict__ bias,
    u16* __restrict__ C, int ldc, int M, int relu_flag) {
  __shared__ u16 lsA[128 * 32];   // 8 KB
  __shared__ u16 lsB[256 * 32];   // 16 KB
  int tid = threadIdx.x;
  int lane = tid & 63, w = tid >> 6;
  int bm = blockIdx.x;
  int wm = (w & 1) << 6, wn = (w >> 1) << 6;
  int ln15 = lane & 15, quad = lane >> 4;

  f32x4 acc[4][4] = {};

  int r = tid >> 2;                         // 0..127
  int c = (tid & 3) ^ (r & 3);              // content chunk for this slot
  const u16* gA = A + (long)min(bm * 128 + r, M - 1) * lda + c * 8;
  const u16* gB0 = BT + (long)r * K + c * 8;
  const u16* gB1 = BT + (long)(r + 128) * K + c * 8;   // (r+128)&3 == r&3
  u16* lA = lsA + w * 512;                  // wave-uniform bases
  u16* lB0 = lsB + w * 512;
  u16* lB1 = lsB + 4096 + w * 512;
  int swz = (quad ^ (ln15 & 3)) << 3;

  for (int k0 = 0; k0 < K; k0 += 32) {
    async16(gA + k0, lA);
    async16(gB0 + k0, lB0);
    async16(gB1 + k0, lB1);
    __syncthreads();
    bf16x8 af[4], bfr[4];
#pragma unroll
    for (int t = 0; t < 4; t++) {
      af[t]  = *(const bf16x8*)(lsA + (wm + t * 16 + ln15) * 32 + swz);
      bfr[t] = *(const bf16x8*)(lsB + (wn + t * 16 + ln15) * 32 + swz);
    }
#pragma unroll
    for (int mt = 0; mt < 4; mt++)
#pragma unroll
      for (int nt = 0; nt < 4; nt++)
        acc[mt][nt] = __builtin_amdgcn_mfma_f32_16x16x32_bf16(af[mt], bfr[nt], acc[mt][nt], 0, 0, 0);
    __syncthreads();
  }

  float bv[4];
#pragma unroll
  for (int nt = 0; nt < 4; nt++)
    bv[nt] = bf2f(bias[wn + nt * 16 + ln15]);

#pragma unroll
  for (int mt = 0; mt < 4; mt++) {
    int row0 = bm * 128 + wm + mt * 16 + quad * 4;
#pragma unroll
    for (int rr = 0; rr < 4; rr++) {
      int row = row0 + rr;
      if (row < M) {
#pragma unroll
        for (int nt = 0; nt < 4; nt++) {
          float v = acc[mt][nt][rr] + bv[nt];
          if (relu_flag) v = fmaxf(v, 0.f);
          C[(long)row * ldc + wn + nt * 16 + ln15] = f2bf(v);
        }
      }
    }
  }
}

// ---------------- per-layer global max pool (2 blocks per graph) ----------------
__global__ void pool_kernel(const u16* __restrict__ h, const int* __restrict__ gs,
                            u16* __restrict__ g_pool, int l) {
  int g = blockIdx.x >> 1, half = blockIdx.x & 1;
  int chunk = threadIdx.x & 15;        // 16 chunks x 8 ch = 128 channels per block
  int rg = threadIdx.x >> 4;           // 64 row-groups
  int beg = gs[g], end = gs[g + 1];
  s16x8 m = (s16x8)(short)0;
  const u16* hp = h + half * 128 + chunk * 8;
  for (int n = beg + rg; n < end; n += 64)
    m = vmax8(m, *(const s16x8*)(hp + (long)n * 512));
  __shared__ s16x8 red[64][16];
  red[rg][chunk] = m;
  __syncthreads();
  for (int s = 32; s >= 1; s >>= 1) {
    if (rg < s) red[rg][chunk] = vmax8(red[rg][chunk], red[rg + s][chunk]);
    __syncthreads();
  }
  if (rg == 0)
    *(s16x8*)(g_pool + g * 1024 + l * 256 + half * 128 + chunk * 8) = red[0][chunk];
}

// ---------------- fc1 split-K GEMM: 8 blocks, f32 partials ----------------
__global__ __launch_bounds__(256) void fc1_gemm(
    const u16* __restrict__ A,      // gpool [128][1024] bf16
    const u16* __restrict__ BT,     // fc1WT [256][1024]
    float* __restrict__ Cpart) {    // [4][128][256]
  __shared__ u16 lsA[128 * 32];
  __shared__ u16 lsB[128 * 32];
  int tid = threadIdx.x;
  int lane = tid & 63, w = tid >> 6;
  int slice = blockIdx.x >> 1, bn = blockIdx.x & 1;
  int wm = (w & 1) << 6, wn = (w >> 1) << 6;
  int ln15 = lane & 15, quad = lane >> 4;

  f32x4 acc[4][4] = {};

  int cm = lane >> 2;
  int ck = (lane & 3) << 3;
  int kb = slice * 256;

  const u16* gA0 = A + (long)(w * 16 + cm) * 1024 + kb + ck;
  const u16* gA1 = A + (long)((w + 4) * 16 + cm) * 1024 + kb + ck;
  const u16* gB0 = BT + (long)(bn * 128 + w * 16 + cm) * 1024 + kb + ck;
  const u16* gB1 = BT + (long)(bn * 128 + (w + 4) * 16 + cm) * 1024 + kb + ck;
  u16* lA0 = lsA + w * 512;
  u16* lA1 = lsA + (w + 4) * 512;
  u16* lB0 = lsB + w * 512;
  u16* lB1 = lsB + (w + 4) * 512;

  for (int k0 = 0; k0 < 256; k0 += 32) {
    async16(gA0 + k0, lA0);
    async16(gA1 + k0, lA1);
    async16(gB0 + k0, lB0);
    async16(gB1 + k0, lB1);
    __syncthreads();
    bf16x8 af[4], bfr[4];
#pragma unroll
    for (int t = 0; t < 4; t++) {
      af[t]  = *(const bf16x8*)(lsA + (wm + t * 16 + ln15) * 32 + quad * 8);
      bfr[t] = *(const bf16x8*)(lsB + (wn + t * 16 + ln15) * 32 + quad * 8);
    }
#pragma unroll
    for (int mt = 0; mt < 4; mt++)
#pragma unroll
      for (int nt = 0; nt < 4; nt++)
        acc[mt][nt] = __builtin_amdgcn_mfma_f32_16x16x32_bf16(af[mt], bfr[nt], acc[mt][nt], 0, 0, 0);
    __syncthreads();
  }

  float* Cb = Cpart + slice * (GG * 256);
#pragma unroll
  for (int mt = 0; mt < 4; mt++) {
    int row0 = wm + mt * 16 + quad * 4;
#pragma unroll
    for (int r = 0; r < 4; r++)
#pragma unroll
      for (int nt = 0; nt < 4; nt++)
        Cb[(row0 + r) * 256 + bn * 128 + wn + nt * 16 + ln15] = acc[mt][nt][r];
  }
}

// ---------------- fc2 + head ----------------
__global__ void fc2_head(const float* __restrict__ fc1part,
                         const u16* __restrict__ fc1b,
                         const u16* __restrict__ W,
                         const u16* __restrict__ b,
                         void* __restrict__ outbuf, const int* __restrict__ flags) {
  int g = blockIdx.x, t = threadIdx.x;
  __shared__ float lr[256];
  __shared__ float ps[144];
  __shared__ float sv[18];
  __shared__ float sred[2];
  float v = bf2f(fc1b[t]);
#pragma unroll
  for (int s = 0; s < 4; s++) v += fc1part[s * (GG * 256) + g * 256 + t];
  v = fmaxf(v, 0.f);
  lr[t] = v;
  if (flags[0]) ((float*)outbuf)[4608 + g * 256 + t] = v;
  else          ((u16*)outbuf)[4608 + g * 256 + t] = f2bf(v);
  __syncthreads();
  if (t < 144) {
    int o = t % 18, s = t / 18;
    float acc = 0.f;
    int k0 = s * 32;
#pragma unroll 8
    for (int k = k0; k < k0 + 32; k++)
      acc += lr[k] * bf2f(W[k * 18 + o]);
    ps[t] = acc;
  }
  __syncthreads();
  if (t < 18) {
    float acc = bf2f(b[t]);
#pragma unroll
    for (int s = 0; s < 8; s++) acc += ps[s * 18 + t];
    sv[t] = acc;
  }
  __syncthreads();
  if (t == 0) {
    float mx = sv[0];
    for (int i = 1; i < 18; i++) mx = fmaxf(mx, sv[i]);
    float s = 0.f;
    for (int i = 0; i < 18; i++) s += expf(sv[i] - mx);
    sred[0] = mx; sred[1] = logf(s);
  }
  __syncthreads();
  if (t < 18) {
    float raw = sv[t];
    float lsm = raw - sred[0] - sred[1];
    if (flags[0]) {
      ((float*)outbuf)[g * 18 + t] = lsm;
      ((float*)outbuf)[2304 + g * 18 + t] = raw;
    } else {
      ((u16*)outbuf)[g * 18 + t] = f2bf(lsm);
      ((u16*)outbuf)[2304 + g * 18 + t] = f2bf(raw);
    }
  }
}

extern "C" void kernel_launch(void* const* d_in, const int* in_sizes, int n_in,
                              void* d_out, int out_size, void* d_ws, size_t ws_size,
                              hipStream_t stream) {
  (void)in_sizes; (void)n_in; (void)out_size; (void)ws_size;
  const void* x = d_in[0];
  const void* ei = d_in[1];
  const void* batch = d_in[2];
  const void *Wl[4], *bl[4], *Wr[4], *Wm[4], *bm[4];
  for (int l = 0; l < 4; l++) {
    Wl[l] = d_in[3 + l * 5 + 0];
    bl[l] = d_in[3 + l * 5 + 1];
    Wr[l] = d_in[3 + l * 5 + 2];
    Wm[l] = d_in[3 + l * 5 + 3];
    bm[l] = d_in[3 + l * 5 + 4];
  }
  const void* fc1W = d_in[23];
  const void* fc1b = d_in[24];
  const void* fc2W = d_in[25];
  const void* fc2b = d_in[26];

  char* ws = (char*)d_ws;
  size_t off = 0;
  auto alloc = [&](size_t bytes) -> void* {
    void* p = ws + off;
    off = (off + bytes + 255) & ~(size_t)255;
    return p;
  };
  int* flags       = (int*)alloc(16);
  int* row_ptr     = (int*)alloc((NN + 1) * sizeof(int));
  int* bucket_cnt  = (int*)alloc(NB * sizeof(int));
  int* bucket_base = (int*)alloc((NB + 1) * sizeof(int));
  int* bucket_cur  = (int*)alloc(NB * sizeof(int));
  unsigned* bucket_buf = (unsigned*)alloc((size_t)EE * sizeof(unsigned));
  int* col_src = (int*)alloc((size_t)EE * sizeof(int));
  int* src32   = (int*)alloc((size_t)EE * sizeof(int));
  int* dst32   = (int*)alloc((size_t)EE * sizeof(int));
  int* batch32 = (int*)alloc(NN * sizeof(int));
  int* gs      = (int*)alloc((GG + 1) * sizeof(int));
  u16* WcatT[4]; for (int l = 0; l < 4; l++) WcatT[l] = (u16*)alloc(256 * 512 * 2);
  u16* WmT[4];   for (int l = 0; l < 4; l++) WmT[l]   = (u16*)alloc(256 * 256 * 2);
  u16* bl_bf[4]; for (int l = 0; l < 4; l++) bl_bf[l] = (u16*)alloc(256 * 2);
  u16* bm_bf[4]; for (int l = 0; l < 4; l++) bm_bf[l] = (u16*)alloc(256 * 2);
  u16* fc1WT   = (u16*)alloc(256 * 1024 * 2);
  u16* fc1b_bf = (u16*)alloc(256 * 2);
  u16* fc2W_bf = (u16*)alloc(256 * 18 * 2);
  u16* fc2b_bf = (u16*)alloc(18 * 2);
  u16* xk      = (u16*)alloc((size_t)NN * DF * 2);
  u16* Acat    = (u16*)alloc((size_t)NN * 512 * 2);
  u16* tmp     = (u16*)alloc((size_t)NN * 256 * 2);
  u16* gpool   = (u16*)alloc(GG * 1024 * 2);
  float* fc1part = (float*)alloc(4 * GG * 256 * sizeof(float));

  detect_kernel<<<2, 256, 0, stream>>>((const u16*)x, (const unsigned*)ei, flags, bucket_cnt);

  TransArgs TA;
  for (int l = 0; l < 4; l++) {
    TA.Wl[l] = Wl[l]; TA.Wr[l] = Wr[l]; TA.Wm[l] = Wm[l];
    TA.WcatT[l] = WcatT[l]; TA.WmT[l] = WmT[l];
  }
  TA.fc1W = fc1W; TA.fc1WT = fc1WT;
  transpose_w<<<240, 256, 0, stream>>>(TA, flags);

  PrepArgs PA;
  int blk = 0, si = 0;
  auto addseg = [&](const void* s, u16* d, int n) {
    PA.s[si].src = s; PA.s[si].dst = d; PA.s[si].start_blk = blk; PA.s[si].n = n;
    blk += (n + 255) / 256; si++;
  };
  addseg(fc2W, fc2W_bf, 256 * 18);
  for (int l = 0; l < 4; l++) addseg(bl[l], bl_bf[l], 256);
  for (int l = 0; l < 4; l++) addseg(bm[l], bm_bf[l], 256);
  addseg(fc1b, fc1b_bf, 256);
  addseg(fc2b, fc2b_bf, 18);
  PA.nseg = si; PA.conv_blocks = blk;
  PA.x = x; PA.acat_x = Acat + DF; PA.xk = xk;
  PA.ei = ei; PA.batch = batch;
  PA.src32 = src32; PA.dst32 = dst32; PA.batch32 = batch32; PA.bucket_cnt = bucket_cnt;
  prep_all<<<PA.conv_blocks + 3125 + 391, 256, 0, stream>>>(PA, flags);

  bucket_scan<<<1, 256, 0, stream>>>(bucket_cnt, bucket_base, bucket_cur, batch32, gs);
  bucket_pass1<<<391, 256, 0, stream>>>(src32, dst32, bucket_cur, bucket_buf);
  bucket_pass2<<<NB, 256, 0, stream>>>(bucket_buf, bucket_base, col_src, row_ptr);

  int segblocks = (NN + 3) / 4;
  int gemmgrid = (NN + 127) / 128;    // 391

  for (int l = 0; l < 4; l++) {
    if (l == 0) {
      segmax_kernel<16, true><<<segblocks, 256, 0, stream>>>(xk, DF, row_ptr, col_src,
                                                             Acat, 512, NN);
    } else {
      segmax_kernel<32, false><<<segblocks, 256, 0, stream>>>(Acat + 256, 512, row_ptr, col_src,
                                                              Acat, 512, NN);
    }
    int K = (l == 0) ? 256 : 512;
    gemm256w<<<gemmgrid, 512, 0, stream>>>(Acat, 512, K, WcatT[l], bl_bf[l], tmp, 256, NN, 0);
    gemm256w<<<gemmgrid, 512, 0, stream>>>(tmp, 256, 256, WmT[l], bm_bf[l], Acat + 256, 512, NN, 1);
    pool_kernel<<<GG * 2, 1024, 0, stream>>>(Acat + 256, gs, gpool, l);
  }

  fc1_gemm<<<8, 256, 0, stream>>>(gpool, fc1WT, fc1part);
  fc2_head<<<GG, 256, 0, stream>>>(fc1part, fc1b_bf, fc2W_bf, fc2b_bf, d_out, flags);
}

// Round 14
// 535.520 us; speedup vs baseline: 1.1514x; 1.0318x over previous
//
#include <hip/hip_runtime.h>
#include <stdint.h>

#define NN 50000
#define EE 800000
#define GG 128
#define DF 128
#define DE 256
#define NB 196                       // dst>>8 buckets (256-node ranges)

typedef unsigned short u16;
typedef __bf16 bf16x8 __attribute__((ext_vector_type(8)));
typedef float f32x4 __attribute__((ext_vector_type(4)));
typedef short s16x8 __attribute__((ext_vector_type(8)));

__device__ __forceinline__ float bf2f(u16 u) {
  union { unsigned int i; float f; } x; x.i = ((unsigned int)u) << 16; return x.f;
}
__device__ __forceinline__ u16 f2bf(float f) {
  union { float f; unsigned int i; } x; x.f = f;
  unsigned int i = x.i;
  return (u16)((i + 0x7fffu + ((i >> 16) & 1u)) >> 16);
}

// global -> LDS DMA, 16B/lane; LDS ptr must be WAVE-UNIFORM, HW adds lane*16
__device__ __forceinline__ void async16(const void* g, void* l) {
  __builtin_amdgcn_global_load_lds(
      (const __attribute__((address_space(1))) void*)g,
      (__attribute__((address_space(3))) void*)l,
      16, 0, 0);
}

__device__ __forceinline__ s16x8 vmax8(s16x8 a, s16x8 b) {
  return __builtin_elementwise_max(a, b);   // v_pk_max_i16
}

// ---------------- detect (block 0) + bucket_cnt zero (block 1) ----------------
__global__ void detect_kernel(const u16* __restrict__ xr,
                              const unsigned* __restrict__ ei_words,
                              int* __restrict__ flags, int* __restrict__ bucket_cnt) {
  int tid = threadIdx.x;
  if (blockIdx.x == 1) {
    if (tid < NB) bucket_cnt[tid] = 0;
    return;
  }
  __shared__ int red[2];
  if (tid < 2) red[tid] = 0;
  __syncthreads();
  int found = 0;
  for (int it = 0; it < 32; it++) {
    int i = it * 256 + tid;
    u16 a = xr[2 * i], b = xr[2 * i + 1];
    if (((a >> 7) & 0xFFu) == 0xFFu) found = 1;
    if (((b >> 7) & 0xFFu) == 0xFFu) found = 1;
  }
  if (__ballot(found)) { if ((tid & 63) == 0) atomicOr(&red[0], 1); }
  int nz = 0;
  if (tid < 128) {
    for (int j = 0; j < 4; j++) {
      unsigned w = ei_words[2 * (tid * 4 + j) + 1];
      if (w != 0u) nz = 1;
    }
  }
  if (__ballot(nz)) { if ((tid & 63) == 0) atomicOr(&red[1], 1); }
  __syncthreads();
  if (tid == 0) { flags[0] = red[0]; flags[1] = red[1]; }
}

__device__ __forceinline__ u16 ldw(const void* p, int idx, int f) {
  return f ? f2bf(((const float*)p)[idx]) : ((const u16*)p)[idx];
}

// ---------------- prep: small conversions + x conversion (16B/thread) + edges ----------------
struct ConvSeg { const void* src; u16* dst; int start_blk; int n; };

struct PrepArgs {
  ConvSeg s[12]; int nseg; int conv_blocks;
  const void* x; u16* acat_x; u16* xk;
  const void* ei; const void* batch;
  int* src32; int* dst32; int* batch32; int* bucket_cnt;
};

__global__ void prep_all(PrepArgs A, const int* __restrict__ flags) {
  int f = flags[0];
  int tid = threadIdx.x;
  int b = blockIdx.x;

  if (b < A.conv_blocks) {
    for (int i = 0; i < A.nseg; i++) {
      int nb = (A.s[i].n + 255) >> 8;
      if (b >= A.s[i].start_blk && b < A.s[i].start_blk + nb) {
        int idx = ((b - A.s[i].start_blk) << 8) + tid;
        if (idx < A.s[i].n) A.s[i].dst[idx] = ldw(A.s[i].src, idx, f);
        return;
      }
    }
    return;
  }
  b -= A.conv_blocks;

  if (b < 3125) {                       // x: 8 elems/thread, vectorized
    int i = (b * 256 + tid) * 8;        // NN*DF = 6,400,000 = 3125*256*8 exactly
    int node = i >> 7, d = i & 127;
    union { u16 u[8]; uint4 v; } o, kx;
    if (f) {
      const float4* xp = (const float4*)((const float*)A.x + i);
      float4 a = xp[0], q = xp[1];
      o.u[0] = f2bf(a.x); o.u[1] = f2bf(a.y); o.u[2] = f2bf(a.z); o.u[3] = f2bf(a.w);
      o.u[4] = f2bf(q.x); o.u[5] = f2bf(q.y); o.u[6] = f2bf(q.z); o.u[7] = f2bf(q.w);
    } else {
      o.v = *(const uint4*)((const u16*)A.x + i);
    }
#pragma unroll
    for (int j = 0; j < 8; j++) {
      short s = (short)o.u[j];
      kx.u[j] = (u16)(s ^ ((s >> 15) & 0x7FFF));
    }
    *(uint4*)(A.acat_x + (long)node * 512 + d) = o.v;
    *(uint4*)(A.xk + i) = kx.v;
    return;
  }
  b -= 3125;

  // edges: 391 blocks x 2048 edges, block-local bucket histogram
  __shared__ int h[NB];
  if (tid < NB) h[tid] = 0;
  __syncthreads();
  int i64 = (flags[1] == 0);
  int e0 = b * 2048;
  for (int j = 0; j < 8; j++) {
    int i = e0 + j * 256 + tid;
    if (i < EE) {
      int s, d;
      if (i64) {
        s = (int)((const long long*)A.ei)[i];
        d = (int)((const long long*)A.ei)[EE + i];
      } else {
        s = ((const int*)A.ei)[i];
        d = ((const int*)A.ei)[EE + i];
      }
      s = min(max(s, 0), NN - 1);
      d = min(max(d, 0), NN - 1);
      A.src32[i] = s;
      A.dst32[i] = d;
      atomicAdd(&h[d >> 8], 1);
    }
    if (i < NN) {
      int bv = i64 ? (int)((const long long*)A.batch)[i] : ((const int*)A.batch)[i];
      A.batch32[i] = min(max(bv, 0), GG - 1);
    }
  }
  __syncthreads();
  if (tid < NB) atomicAdd(&A.bucket_cnt[tid], h[tid]);
}

// ---------------- LDS-tiled weight transposes ----------------
struct TransArgs {
  const void* Wl[4]; const void* Wr[4]; const void* Wm[4]; const void* fc1W;
  u16* WcatT[4]; u16* WmT[4]; u16* fc1WT;
};

__global__ __launch_bounds__(256) void transpose_w(TransArgs T, const int* __restrict__ flags) {
  int f = flags[0];
  __shared__ u16 tile[64][65];
  int b = blockIdx.x;
  const void* src; u16* dst; int kt, ntile, Kd; int krow_off = 0;
  if (b < 16) {
    kt = b >> 2; ntile = b & 3; Kd = 256;
    if (kt * 64 < 128) { src = T.Wl[0]; } else { src = T.Wr[0]; krow_off = 128; }
    dst = T.WcatT[0];
  } else if (b < 112) {
    int l = 1 + (b - 16) / 32; int t = (b - 16) % 32;
    kt = t >> 2; ntile = t & 3; Kd = 512;
    if (kt * 64 < 256) { src = T.Wl[l]; } else { src = T.Wr[l]; krow_off = 256; }
    dst = T.WcatT[l];
  } else if (b < 176) {
    int l = (b - 112) / 16; int t = (b - 112) % 16;
    kt = t >> 2; ntile = t & 3; Kd = 256;
    src = T.Wm[l]; dst = T.WmT[l];
  } else {
    int t = b - 176;
    kt = t >> 2; ntile = t & 3; Kd = 1024;
    src = T.fc1W; dst = T.fc1WT;
  }
  int cj = threadIdx.x & 63, rp = threadIdx.x >> 6;
#pragma unroll 4
  for (int p = 0; p < 16; p++) {
    int krow = kt * 64 + p * 4 + rp;
    tile[p * 4 + rp][cj] = ldw(src, (krow - krow_off) * 256 + ntile * 64 + cj, f);
  }
  __syncthreads();
#pragma unroll 4
  for (int p = 0; p < 16; p++) {
    int nrow = ntile * 64 + p * 4 + rp;
    dst[(long)nrow * Kd + kt * 64 + cj] = tile[cj][p * 4 + rp];
  }
}

// ---------------- bucket scan (+ graph starts) ----------------
__global__ void bucket_scan(const int* __restrict__ bucket_cnt, int* __restrict__ bucket_base,
                            int* __restrict__ bucket_cur,
                            const int* __restrict__ batch, int* __restrict__ gs) {
  __shared__ int sh[256];
  int tid = threadIdx.x;
  int x = (tid < NB) ? bucket_cnt[tid] : 0;
  sh[tid] = x;
  __syncthreads();
  for (int off = 1; off < 256; off <<= 1) {
    int v = (tid >= off) ? sh[tid - off] : 0;
    __syncthreads();
    sh[tid] += v;
    __syncthreads();
  }
  if (tid < NB) { bucket_base[tid] = sh[tid] - x; bucket_cur[tid] = sh[tid] - x; }
  if (tid == 0) bucket_base[NB] = EE;
  if (tid <= GG) {
    int g = tid, lo = 0, hi = NN;
    while (lo < hi) { int mid = (lo + hi) >> 1; if (batch[mid] < g) lo = mid + 1; else hi = mid; }
    gs[g] = lo;
  }
}

// ---------------- pass1: scatter edges into bucket-contiguous regions ----------------
__global__ __launch_bounds__(256) void bucket_pass1(
    const int* __restrict__ src32, const int* __restrict__ dst32,
    int* __restrict__ bucket_cur, unsigned* __restrict__ bucket_buf) {
  __shared__ int lcnt[NB];
  __shared__ int lbase[NB];
  int tid = threadIdx.x, b = blockIdx.x;
  if (tid < NB) lcnt[tid] = 0;
  __syncthreads();
  int e0 = b * 2048;
  int lofs[8]; unsigned pk[8]; int bk[8];
#pragma unroll
  for (int j = 0; j < 8; j++) {
    int i = e0 + j * 256 + tid;
    if (i < EE) {
      int s = src32[i], d = dst32[i];
      bk[j] = d >> 8;
      pk[j] = ((unsigned)s << 8) | (unsigned)(d & 255);
      lofs[j] = atomicAdd(&lcnt[bk[j]], 1);
    } else bk[j] = -1;
  }
  __syncthreads();
  if (tid < NB) lbase[tid] = atomicAdd(&bucket_cur[tid], lcnt[tid]);
  __syncthreads();
#pragma unroll
  for (int j = 0; j < 8; j++)
    if (bk[j] >= 0)
      bucket_buf[lbase[bk[j]] + lofs[j]] = pk[j];
}

// ---------------- pass2: per-bucket local CSR -> row_ptr + col_src ----------------
__global__ __launch_bounds__(256) void bucket_pass2(
    const unsigned* __restrict__ bucket_buf, const int* __restrict__ bucket_base,
    int* __restrict__ col_src, int* __restrict__ row_ptr) {
  __shared__ int cnt[256];
  __shared__ int sh[256];
  __shared__ int cur[256];
  int tid = threadIdx.x, b = blockIdx.x;
  int ebase = bucket_base[b], eend = bucket_base[b + 1];
  cnt[tid] = 0;
  __syncthreads();
  for (int e = ebase + tid; e < eend; e += 256)
    atomicAdd(&cnt[bucket_buf[e] & 255u], 1);
  __syncthreads();
  int x = cnt[tid];
  sh[tid] = x;
  __syncthreads();
  for (int off = 1; off < 256; off <<= 1) {
    int v = (tid >= off) ? sh[tid - off] : 0;
    __syncthreads();
    sh[tid] += v;
    __syncthreads();
  }
  int node = b * 256 + tid;
  if (node < NN) row_ptr[node + 1] = ebase + sh[tid];
  cur[tid] = ebase + sh[tid] - x;
  __syncthreads();
  for (int e = ebase + tid; e < eend; e += 256) {
    unsigned p = bucket_buf[e];
    int slot = atomicAdd(&cur[p & 255u], 1);
    col_src[slot] = (int)(p >> 8);
  }
  if (b == 0 && tid == 0) row_ptr[0] = 0;
}

// ---------------- per-node max aggregation (packed i16, 4-deep ILP) ----------------
template <int LPR, bool KEYED>
__global__ __launch_bounds__(256) void segmax_kernel(
    const u16* __restrict__ feat, int fstride,
    const int* __restrict__ row_ptr, const int* __restrict__ col_src,
    u16* __restrict__ agg_out, int ostride, int n) {
  constexpr int R = 64 / LPR;
  int node = blockIdx.x * 4 + (threadIdx.x >> 6);
  if (node >= n) return;
  int lane = threadIdx.x & 63;
  int sub = lane / LPR;
  int cp = lane % LPR;
  int beg = row_ptr[node], end = row_ptr[node + 1];
  s16x8 m = (s16x8)(short)(KEYED ? (short)0x807F : (short)0);
  const u16* fb = feat + cp * 8;

  int e = beg + sub;
  for (; e + 3 * R < end; e += 4 * R) {
    int s0 = col_src[e];
    int s1 = col_src[e + R];
    int s2 = col_src[e + 2 * R];
    int s3 = col_src[e + 3 * R];
    s16x8 v0 = *(const s16x8*)(fb + (long)s0 * fstride);
    s16x8 v1 = *(const s16x8*)(fb + (long)s1 * fstride);
    s16x8 v2 = *(const s16x8*)(fb + (long)s2 * fstride);
    s16x8 v3 = *(const s16x8*)(fb + (long)s3 * fstride);
    m = vmax8(m, vmax8(vmax8(v0, v1), vmax8(v2, v3)));
  }
  for (; e < end; e += R)
    m = vmax8(m, *(const s16x8*)(fb + (long)col_src[e] * fstride));

#pragma unroll
  for (int d = LPR; d < 64; d <<= 1) {
    union { s16x8 s; int i[4]; } t;
    t.s = m;
#pragma unroll
    for (int j = 0; j < 4; j++) t.i[j] = __shfl_xor(t.i[j], d);
    m = vmax8(m, t.s);
  }

  if (sub == 0) {
    if (KEYED) {
      if (beg == end) {
        m = (s16x8)(short)0;
      } else {
        s16x8 sp = (m >> 15) & (short)0x7FFF;
        m = m ^ sp;
      }
    }
    *(s16x8*)(agg_out + (long)node * ostride + cp * 8) = m;
  }
}

// ---------------- MFMA GEMM: 128x256 tile, 512 threads, BK=64, row-XOR chunk swizzle ----
// LDS 48KB -> 3 blocks/CU; 8 barrier-pairs for K=512 (half of BK=32 version).
// Staging slot (row, pchunk=lane&7) holds logical chunk j = pchunk ^ (row&7).
// Reader: phys chunk = ((kh*4+quad) ^ (ln15&7)); rows r,r+8 alias -> 2-way (free).
__global__ __launch_bounds__(512) void gemm256w(
    const u16* __restrict__ A, int lda, int K,
    const u16* __restrict__ BT,          // [256][K]
    const u16* __restrict__ bias,
    u16* __restrict__ C, int ldc, int M, int relu_flag) {
  __shared__ u16 lsA[128 * 64];   // 16 KB
  __shared__ u16 lsB[256 * 64];   // 32 KB
  int tid = threadIdx.x;
  int lane = tid & 63, w = tid >> 6;      // 8 waves
  int bm = blockIdx.x;
  int wm = (w & 1) << 6, wn = (w >> 1) << 6;
  int ln15 = lane & 15, quad = lane >> 4;

  f32x4 acc[4][4] = {};

  int riw = lane >> 3;                    // row within wave's 8-row slab
  int j = (lane & 7) ^ riw;               // logical chunk this lane fetches
  // A rows: ar*64 + w*8 + riw (ar in {0,1}); B rows: br*64 + w*8 + riw (br in 0..3)
  int ra0 = min(bm * 128 + w * 8 + riw, M - 1);
  int ra1 = min(bm * 128 + 64 + w * 8 + riw, M - 1);
  const u16* gA0 = A + (long)ra0 * lda + j * 8;
  const u16* gA1 = A + (long)ra1 * lda + j * 8;
  const u16* gB0 = BT + (long)(w * 8 + riw) * K + j * 8;
  const u16* gB1 = BT + (long)(64 + w * 8 + riw) * K + j * 8;
  const u16* gB2 = BT + (long)(128 + w * 8 + riw) * K + j * 8;
  const u16* gB3 = BT + (long)(192 + w * 8 + riw) * K + j * 8;
  u16* lA0 = lsA + (w * 8) * 64;          // wave-uniform bases (HW adds lane*16B)
  u16* lA1 = lsA + (64 + w * 8) * 64;
  u16* lB0 = lsB + (w * 8) * 64;
  u16* lB1 = lsB + (64 + w * 8) * 64;
  u16* lB2 = lsB + (128 + w * 8) * 64;
  u16* lB3 = lsB + (192 + w * 8) * 64;
  int swz7 = ln15 & 7;

  for (int k0 = 0; k0 < K; k0 += 64) {
    async16(gA0 + k0, lA0);
    async16(gA1 + k0, lA1);
    async16(gB0 + k0, lB0);
    async16(gB1 + k0, lB1);
    async16(gB2 + k0, lB2);
    async16(gB3 + k0, lB3);
    __syncthreads();
#pragma unroll
    for (int kh = 0; kh < 2; kh++) {
      int pc = (((kh << 2) | quad) ^ swz7) << 3;
      bf16x8 af[4], bfr[4];
#pragma unroll
      for (int t = 0; t < 4; t++) {
        af[t]  = *(const bf16x8*)(lsA + (wm + t * 16 + ln15) * 64 + pc);
        bfr[t] = *(const bf16x8*)(lsB + (wn + t * 16 + ln15) * 64 + pc);
      }
#pragma unroll
      for (int mt = 0; mt < 4; mt++)
#pragma unroll
        for (int nt = 0; nt < 4; nt++)
          acc[mt][nt] = __builtin_amdgcn_mfma_f32_16x16x32_bf16(af[mt], bfr[nt], acc[mt][nt], 0, 0, 0);
    }
    __syncthreads();
  }

  float bv[4];
#pragma unroll
  for (int nt = 0; nt < 4; nt++)
    bv[nt] = bf2f(bias[wn + nt * 16 + ln15]);

#pragma unroll
  for (int mt = 0; mt < 4; mt++) {
    int row0 = bm * 128 + wm + mt * 16 + quad * 4;
#pragma unroll
    for (int rr = 0; rr < 4; rr++) {
      int row = row0 + rr;
      if (row < M) {
#pragma unroll
        for (int nt = 0; nt < 4; nt++) {
          float v = acc[mt][nt][rr] + bv[nt];
          if (relu_flag) v = fmaxf(v, 0.f);
          C[(long)row * ldc + wn + nt * 16 + ln15] = f2bf(v);
        }
      }
    }
  }
}

// ---------------- per-layer global max pool (2 blocks per graph) ----------------
__global__ void pool_kernel(const u16* __restrict__ h, const int* __restrict__ gs,
                            u16* __restrict__ g_pool, int l) {
  int g = blockIdx.x >> 1, half = blockIdx.x & 1;
  int chunk = threadIdx.x & 15;
  int rg = threadIdx.x >> 4;
  int beg = gs[g], end = gs[g + 1];
  s16x8 m = (s16x8)(short)0;
  const u16* hp = h + half * 128 + chunk * 8;
  for (int n = beg + rg; n < end; n += 64)
    m = vmax8(m, *(const s16x8*)(hp + (long)n * 512));
  __shared__ s16x8 red[64][16];
  red[rg][chunk] = m;
  __syncthreads();
  for (int s = 32; s >= 1; s >>= 1) {
    if (rg < s) red[rg][chunk] = vmax8(red[rg][chunk], red[rg + s][chunk]);
    __syncthreads();
  }
  if (rg == 0)
    *(s16x8*)(g_pool + g * 1024 + l * 256 + half * 128 + chunk * 8) = red[0][chunk];
}

// ---------------- fc1 split-K GEMM: 8 blocks, f32 partials ----------------
__global__ __launch_bounds__(256) void fc1_gemm(
    const u16* __restrict__ A,      // gpool [128][1024] bf16
    const u16* __restrict__ BT,     // fc1WT [256][1024]
    float* __restrict__ Cpart) {    // [4][128][256]
  __shared__ u16 lsA[128 * 32];
  __shared__ u16 lsB[128 * 32];
  int tid = threadIdx.x;
  int lane = tid & 63, w = tid >> 6;
  int slice = blockIdx.x >> 1, bn = blockIdx.x & 1;
  int wm = (w & 1) << 6, wn = (w >> 1) << 6;
  int ln15 = lane & 15, quad = lane >> 4;

  f32x4 acc[4][4] = {};

  int cm = lane >> 2;
  int ck = (lane & 3) << 3;
  int kb = slice * 256;

  const u16* gA0 = A + (long)(w * 16 + cm) * 1024 + kb + ck;
  const u16* gA1 = A + (long)((w + 4) * 16 + cm) * 1024 + kb + ck;
  const u16* gB0 = BT + (long)(bn * 128 + w * 16 + cm) * 1024 + kb + ck;
  const u16* gB1 = BT + (long)(bn * 128 + (w + 4) * 16 + cm) * 1024 + kb + ck;
  u16* lA0 = lsA + w * 512;
  u16* lA1 = lsA + (w + 4) * 512;
  u16* lB0 = lsB + w * 512;
  u16* lB1 = lsB + (w + 4) * 512;

  for (int k0 = 0; k0 < 256; k0 += 32) {
    async16(gA0 + k0, lA0);
    async16(gA1 + k0, lA1);
    async16(gB0 + k0, lB0);
    async16(gB1 + k0, lB1);
    __syncthreads();
    bf16x8 af[4], bfr[4];
#pragma unroll
    for (int t = 0; t < 4; t++) {
      af[t]  = *(const bf16x8*)(lsA + (wm + t * 16 + ln15) * 32 + quad * 8);
      bfr[t] = *(const bf16x8*)(lsB + (wn + t * 16 + ln15) * 32 + quad * 8);
    }
#pragma unroll
    for (int mt = 0; mt < 4; mt++)
#pragma unroll
      for (int nt = 0; nt < 4; nt++)
        acc[mt][nt] = __builtin_amdgcn_mfma_f32_16x16x32_bf16(af[mt], bfr[nt], acc[mt][nt], 0, 0, 0);
    __syncthreads();
  }

  float* Cb = Cpart + slice * (GG * 256);
#pragma unroll
  for (int mt = 0; mt < 4; mt++) {
    int row0 = wm + mt * 16 + quad * 4;
#pragma unroll
    for (int r = 0; r < 4; r++)
#pragma unroll
      for (int nt = 0; nt < 4; nt++)
        Cb[(row0 + r) * 256 + bn * 128 + wn + nt * 16 + ln15] = acc[mt][nt][r];
  }
}

// ---------------- fc2 + head ----------------
__global__ void fc2_head(const float* __restrict__ fc1part,
                         const u16* __restrict__ fc1b,
                         const u16* __restrict__ W,
                         const u16* __restrict__ b,
                         void* __restrict__ outbuf, const int* __restrict__ flags) {
  int g = blockIdx.x, t = threadIdx.x;
  __shared__ float lr[256];
  __shared__ float ps[144];
  __shared__ float sv[18];
  __shared__ float sred[2];
  float v = bf2f(fc1b[t]);
#pragma unroll
  for (int s = 0; s < 4; s++) v += fc1part[s * (GG * 256) + g * 256 + t];
  v = fmaxf(v, 0.f);
  lr[t] = v;
  if (flags[0]) ((float*)outbuf)[4608 + g * 256 + t] = v;
  else          ((u16*)outbuf)[4608 + g * 256 + t] = f2bf(v);
  __syncthreads();
  if (t < 144) {
    int o = t % 18, s = t / 18;
    float acc = 0.f;
    int k0 = s * 32;
#pragma unroll 8
    for (int k = k0; k < k0 + 32; k++)
      acc += lr[k] * bf2f(W[k * 18 + o]);
    ps[t] = acc;
  }
  __syncthreads();
  if (t < 18) {
    float acc = bf2f(b[t]);
#pragma unroll
    for (int s = 0; s < 8; s++) acc += ps[s * 18 + t];
    sv[t] = acc;
  }
  __syncthreads();
  if (t == 0) {
    float mx = sv[0];
    for (int i = 1; i < 18; i++) mx = fmaxf(mx, sv[i]);
    float s = 0.f;
    for (int i = 0; i < 18; i++) s += expf(sv[i] - mx);
    sred[0] = mx; sred[1] = logf(s);
  }
  __syncthreads();
  if (t < 18) {
    float raw = sv[t];
    float lsm = raw - sred[0] - sred[1];
    if (flags[0]) {
      ((float*)outbuf)[g * 18 + t] = lsm;
      ((float*)outbuf)[2304 + g * 18 + t] = raw;
    } else {
      ((u16*)outbuf)[g * 18 + t] = f2bf(lsm);
      ((u16*)outbuf)[2304 + g * 18 + t] = f2bf(raw);
    }
  }
}

extern "C" void kernel_launch(void* const* d_in, const int* in_sizes, int n_in,
                              void* d_out, int out_size, void* d_ws, size_t ws_size,
                              hipStream_t stream) {
  (void)in_sizes; (void)n_in; (void)out_size; (void)ws_size;
  const void* x = d_in[0];
  const void* ei = d_in[1];
  const void* batch = d_in[2];
  const void *Wl[4], *bl[4], *Wr[4], *Wm[4], *bm[4];
  for (int l = 0; l < 4; l++) {
    Wl[l] = d_in[3 + l * 5 + 0];
    bl[l] = d_in[3 + l * 5 + 1];
    Wr[l] = d_in[3 + l * 5 + 2];
    Wm[l] = d_in[3 + l * 5 + 3];
    bm[l] = d_in[3 + l * 5 + 4];
  }
  const void* fc1W = d_in[23];
  const void* fc1b = d_in[24];
  const void* fc2W = d_in[25];
  const void* fc2b = d_in[26];

  char* ws = (char*)d_ws;
  size_t off = 0;
  auto alloc = [&](size_t bytes) -> void* {
    void* p = ws + off;
    off = (off + bytes + 255) & ~(size_t)255;
    return p;
  };
  int* flags       = (int*)alloc(16);
  int* row_ptr     = (int*)alloc((NN + 1) * sizeof(int));
  int* bucket_cnt  = (int*)alloc(NB * sizeof(int));
  int* bucket_base = (int*)alloc((NB + 1) * sizeof(int));
  int* bucket_cur  = (int*)alloc(NB * sizeof(int));
  unsigned* bucket_buf = (unsigned*)alloc((size_t)EE * sizeof(unsigned));
  int* col_src = (int*)alloc((size_t)EE * sizeof(int));
  int* src32   = (int*)alloc((size_t)EE * sizeof(int));
  int* dst32   = (int*)alloc((size_t)EE * sizeof(int));
  int* batch32 = (int*)alloc(NN * sizeof(int));
  int* gs      = (int*)alloc((GG + 1) * sizeof(int));
  u16* WcatT[4]; for (int l = 0; l < 4; l++) WcatT[l] = (u16*)alloc(256 * 512 * 2);
  u16* WmT[4];   for (int l = 0; l < 4; l++) WmT[l]   = (u16*)alloc(256 * 256 * 2);
  u16* bl_bf[4]; for (int l = 0; l < 4; l++) bl_bf[l] = (u16*)alloc(256 * 2);
  u16* bm_bf[4]; for (int l = 0; l < 4; l++) bm_bf[l] = (u16*)alloc(256 * 2);
  u16* fc1WT   = (u16*)alloc(256 * 1024 * 2);
  u16* fc1b_bf = (u16*)alloc(256 * 2);
  u16* fc2W_bf = (u16*)alloc(256 * 18 * 2);
  u16* fc2b_bf = (u16*)alloc(18 * 2);
  u16* xk      = (u16*)alloc((size_t)NN * DF * 2);
  u16* Acat    = (u16*)alloc((size_t)NN * 512 * 2);
  u16* tmp     = (u16*)alloc((size_t)NN * 256 * 2);
  u16* gpool   = (u16*)alloc(GG * 1024 * 2);
  float* fc1part = (float*)alloc(4 * GG * 256 * sizeof(float));

  detect_kernel<<<2, 256, 0, stream>>>((const u16*)x, (const unsigned*)ei, flags, bucket_cnt);

  TransArgs TA;
  for (int l = 0; l < 4; l++) {
    TA.Wl[l] = Wl[l]; TA.Wr[l] = Wr[l]; TA.Wm[l] = Wm[l];
    TA.WcatT[l] = WcatT[l]; TA.WmT[l] = WmT[l];
  }
  TA.fc1W = fc1W; TA.fc1WT = fc1WT;
  transpose_w<<<240, 256, 0, stream>>>(TA, flags);

  PrepArgs PA;
  int blk = 0, si = 0;
  auto addseg = [&](const void* s, u16* d, int n) {
    PA.s[si].src = s; PA.s[si].dst = d; PA.s[si].start_blk = blk; PA.s[si].n = n;
    blk += (n + 255) / 256; si++;
  };
  addseg(fc2W, fc2W_bf, 256 * 18);
  for (int l = 0; l < 4; l++) addseg(bl[l], bl_bf[l], 256);
  for (int l = 0; l < 4; l++) addseg(bm[l], bm_bf[l], 256);
  addseg(fc1b, fc1b_bf, 256);
  addseg(fc2b, fc2b_bf, 18);
  PA.nseg = si; PA.conv_blocks = blk;
  PA.x = x; PA.acat_x = Acat + DF; PA.xk = xk;
  PA.ei = ei; PA.batch = batch;
  PA.src32 = src32; PA.dst32 = dst32; PA.batch32 = batch32; PA.bucket_cnt = bucket_cnt;
  prep_all<<<PA.conv_blocks + 3125 + 391, 256, 0, stream>>>(PA, flags);

  bucket_scan<<<1, 256, 0, stream>>>(bucket_cnt, bucket_base, bucket_cur, batch32, gs);
  bucket_pass1<<<391, 256, 0, stream>>>(src32, dst32, bucket_cur, bucket_buf);
  bucket_pass2<<<NB, 256, 0, stream>>>(bucket_buf, bucket_base, col_src, row_ptr);

  int segblocks = (NN + 3) / 4;
  int gemmgrid = (NN + 127) / 128;    // 391

  for (int l = 0; l < 4; l++) {
    if (l == 0) {
      segmax_kernel<16, true><<<segblocks, 256, 0, stream>>>(xk, DF, row_ptr, col_src,
                                                             Acat, 512, NN);
    } else {
      segmax_kernel<32, false><<<segblocks, 256, 0, stream>>>(Acat + 256, 512, row_ptr, col_src,
                                                              Acat, 512, NN);
    }
    int K = (l == 0) ? 256 : 512;
    gemm256w<<<gemmgrid, 512, 0, stream>>>(Acat, 512, K, WcatT[l], bl_bf[l], tmp, 256, NN, 0);
    gemm256w<<<gemmgrid, 512, 0, stream>>>(tmp, 256, 256, WmT[l], bm_bf[l], Acat + 256, 512, NN, 1);
    pool_kernel<<<GG * 2, 1024, 0, stream>>>(Acat + 256, gs, gpool, l);
  }

  fc1_gemm<<<8, 256, 0, stream>>>(gpool, fc1WT, fc1part);
  fc2_head<<<GG, 256, 0, stream>>>(fc1part, fc1b_bf, fc2W_bf, fc2b_bf, d_out, flags);
}